// Round 8
// baseline (509.797 us; speedup 1.0000x reference)
//
#include <hip/hip_runtime.h>

#define N 8192
#define IN_F 512
#define OUT_F 128
#define NW (N / 8)
#define SPLITK 8
#define KC 1024
#define LOG2E 1.4426950408889634f
#define LN2 0.6931471805599453f

typedef __attribute__((ext_vector_type(4))) float f32x4;
typedef __attribute__((ext_vector_type(8))) short bf16x8;
typedef __attribute__((ext_vector_type(8))) unsigned short u16x8;

__device__ __forceinline__ short f2bf(float f) {
    union { float f; unsigned u; } c; c.f = f;
    unsigned r = c.u + 0x7FFFu + ((c.u >> 16) & 1u);
    return (short)(r >> 16);
}

__device__ __forceinline__ float exp2fast(float x) {
#if __has_builtin(__builtin_amdgcn_exp2f)
    return __builtin_amdgcn_exp2f(x);
#else
    return __expf(x * LN2);
#endif
}

// ---------------------------------------------------------------- conv_W: W -> WT bf16 [OUT_F][IN_F]
__global__ __launch_bounds__(256) void conv_W(const float* __restrict__ W, short* __restrict__ WT) {
    int idx = blockIdx.x * 256 + threadIdx.x;
    int n = idx & (OUT_F - 1);
    int k = idx >> 7;
    WT[(size_t)n * IN_F + k] = f2bf(W[idx]);
}

// ---------------------------------------------------------------- mkmask: adj int32 -> row-major bitmask (pure stream)
__global__ __launch_bounds__(256) void mkmask(const int* __restrict__ adj,
                                              unsigned char* __restrict__ maskR) {
    const int wave = threadIdx.x >> 6, lane = threadIdx.x & 63;
    const size_t m = (size_t)blockIdx.x * 4 + wave;
    const int4* ap = (const int4*)(adj + m * N);
    unsigned char* mp = maskR + m * NW;
#pragma unroll 4
    for (int it = 0; it < 16; it++) {
        int b4 = it * 128 + lane * 2;
        int4 a0 = ap[b4], a1 = ap[b4 + 1];
        unsigned b = (unsigned)(a0.x > 0) | ((unsigned)(a0.y > 0) << 1) |
                     ((unsigned)(a0.z > 0) << 2) | ((unsigned)(a0.w > 0) << 3) |
                     ((unsigned)(a1.x > 0) << 4) | ((unsigned)(a1.y > 0) << 5) |
                     ((unsigned)(a1.z > 0) << 6) | ((unsigned)(a1.w > 0) << 7);
        mp[it * 64 + lane] = (unsigned char)b;
    }
}

// ---------------------------------------------------------------- gemm_hW: Wh=h@W -> WhT bf16 [OUT_F][N]; fused s,t (x LOG2E)
__global__ __launch_bounds__(256) void gemm_hW(const float* __restrict__ h,
                                               const short* __restrict__ WT,
                                               const float* __restrict__ a,
                                               short* __restrict__ WhT,
                                               float* __restrict__ sOut,
                                               float* __restrict__ tOut) {
    const int tid = threadIdx.x;
    const int wave = tid >> 6, lane = tid & 63;
    const int row16 = lane & 15, kgrp = lane >> 4;
    const int m0 = blockIdx.x * 16;
    const int kbase = wave * 128;

    f32x4 acc[8] = {};
    const float4* hp = (const float4*)(h + (size_t)(m0 + row16) * IN_F + kbase);

#pragma unroll
    for (int kk = 0; kk < 128; kk += 32) {
        float4 u0 = hp[kk / 4 + kgrp * 2];
        float4 u1 = hp[kk / 4 + kgrp * 2 + 1];
        bf16x8 af;
        af[0] = f2bf(u0.x); af[1] = f2bf(u0.y); af[2] = f2bf(u0.z); af[3] = f2bf(u0.w);
        af[4] = f2bf(u1.x); af[5] = f2bf(u1.y); af[6] = f2bf(u1.z); af[7] = f2bf(u1.w);
#pragma unroll
        for (int nt = 0; nt < 8; nt++) {
            bf16x8 bf_ = *(const bf16x8*)(WT + (size_t)(nt * 16 + row16) * IN_F + kbase + kk + kgrp * 8);
            acc[nt] = __builtin_amdgcn_mfma_f32_16x16x32_bf16(af, bf_, acc[nt], 0, 0, 0);
        }
    }

    __shared__ float red[4][16][132];
#pragma unroll
    for (int nt = 0; nt < 8; nt++)
#pragma unroll
        for (int r = 0; r < 4; r++)
            red[wave][kgrp * 4 + r][nt * 16 + row16] = acc[nt][r];
    __syncthreads();

    const int row = tid >> 4, seg = tid & 15;
    float v[8];
#pragma unroll
    for (int e = 0; e < 8; e++) {
        int c = seg * 8 + e;
        v[e] = red[0][row][c] + red[1][row][c] + red[2][row][c] + red[3][row][c];
    }
    float sp = 0.f, tp = 0.f;
#pragma unroll
    for (int e = 0; e < 8; e++) {
        sp += v[e] * a[seg * 8 + e];
        tp += v[e] * a[OUT_F + seg * 8 + e];
    }
    sp += __shfl_xor(sp, 1); tp += __shfl_xor(tp, 1);
    sp += __shfl_xor(sp, 2); tp += __shfl_xor(tp, 2);
    sp += __shfl_xor(sp, 4); tp += __shfl_xor(tp, 4);
    sp += __shfl_xor(sp, 8); tp += __shfl_xor(tp, 8);
    if (seg == 0) {
        sOut[m0 + row] = sp * LOG2E;
        tOut[m0 + row] = tp * LOG2E;
    }
#pragma unroll
    for (int e = 0; e < 8; e++)
        WhT[(size_t)(seg * 8 + e) * N + m0 + row] = f2bf(v[e]);
}

// ---------------------------------------------------------------- attn: barrier-free, register-pipelined
// grid (64, 8), 256 thr = 4 waves; wave = 32M x 128N x 1024K; NO LDS, NO __syncthreads
__global__ __launch_bounds__(256, 2) void attn(const unsigned char* __restrict__ maskR,
                                               const short* __restrict__ WhT,
                                               const float* __restrict__ s,
                                               const float* __restrict__ t,
                                               unsigned short* __restrict__ num,
                                               float* __restrict__ lpart) {
    const int tid = threadIdx.x;
    const int wave = tid >> 6, lane = tid & 63;
    const int row16 = lane & 15, kgrp = lane >> 4;
    const int mw = blockIdx.x * 128 + wave * 32;
    const int ks = blockIdx.y * KC;

    float s_m[2];
    const int4* mp[2];
#pragma unroll
    for (int mi = 0; mi < 2; mi++) {
        int m = mw + mi * 16 + row16;
        s_m[mi] = s[m];
        mp[mi] = (const int4*)(maskR + (size_t)m * NW + (ks >> 3));   // 8 int4s per row-chunk
    }

    const short* Bbase = WhT + ks + kgrp * 8;
    // B register double-buffer, prefetch distance 2 slices
    bf16x8 Bb[2][8];
#pragma unroll
    for (int ni = 0; ni < 8; ni++) {
        Bb[0][ni] = *(const bf16x8*)(Bbase + (size_t)(ni * 16 + row16) * N);
        Bb[1][ni] = *(const bf16x8*)(Bbase + (size_t)(ni * 16 + row16) * N + 32);
    }

    int4 mcur[2], mnxt[2];
#pragma unroll
    for (int mi = 0; mi < 2; mi++) { mcur[mi] = mp[mi][0]; mnxt[mi] = mp[mi][1]; }

    f32x4 acc[2][8] = {};
    float lsum[2] = {0.f, 0.f};
    const float* tbase = t + ks + kgrp * 8;

#pragma unroll
    for (int a = 0; a < 8; a++) {            // each a = one int4 of mask = 4 slices of 32k
        int4 mk[2];
#pragma unroll
        for (int mi = 0; mi < 2; mi++) { mk[mi] = mcur[mi]; mcur[mi] = mnxt[mi]; }
        if (a + 2 < 8) {
#pragma unroll
            for (int mi = 0; mi < 2; mi++) mnxt[mi] = mp[mi][a + 2];
        }
#pragma unroll
        for (int d = 0; d < 4; d++) {
            const int g = a * 4 + d;          // slice 0..31
            // t (L1-hot: 32KB shared by all blocks)
            float4 tA = *(const float4*)(tbase + g * 32);
            float4 tB = *(const float4*)(tbase + g * 32 + 4);
            float tv[8] = { tA.x, tA.y, tA.z, tA.w, tB.x, tB.y, tB.z, tB.w };

#pragma unroll
            for (int mi = 0; mi < 2; mi++) {
                const unsigned mbyte = ((unsigned)((const int*)&mk[mi])[d] >> (kgrp * 8)) & 0xFFu;
                unsigned pu[8];
#pragma unroll
                for (int e = 0; e < 8; e++) {
                    float x = s_m[mi] + tv[e];
                    x = fmaxf(x, 0.2f * x);                   // leaky relu
                    float p = exp2fast(x);                    // s,t pre-scaled by log2e
                    unsigned u = __float_as_uint(p) & 0xFFFF0000u;
                    u = ((mbyte >> e) & 1u) ? u : 0u;
                    lsum[mi] += __uint_as_float(u);           // consistent with numerator
                    pu[e] = u;
                }
                bf16x8 af;
                unsigned* au = (unsigned*)&af;
#pragma unroll
                for (int q = 0; q < 4; q++) au[q] = (pu[2 * q] >> 16) | pu[2 * q + 1];
#pragma unroll
                for (int ni = 0; ni < 8; ni++)
                    acc[mi][ni] = __builtin_amdgcn_mfma_f32_16x16x32_bf16(af, Bb[g & 1][ni], acc[mi][ni], 0, 0, 0);
            }
            // refill the buffer just consumed with slice g+2 (use at g+2 => ~2 slices of latency cover)
            if (g + 2 < 32) {
#pragma unroll
                for (int ni = 0; ni < 8; ni++)
                    Bb[g & 1][ni] = *(const bf16x8*)(Bbase + (size_t)(ni * 16 + row16) * N + (g + 2) * 32);
            }
        }
    }

#pragma unroll
    for (int mi = 0; mi < 2; mi++) {
        float v = lsum[mi];
        v += __shfl_xor(v, 16);
        v += __shfl_xor(v, 32);
        if (kgrp == 0) lpart[(size_t)blockIdx.y * N + mw + mi * 16 + row16] = v;
    }

    unsigned short* np_ = num + ((size_t)blockIdx.y * N + mw) * OUT_F;
#pragma unroll
    for (int mi = 0; mi < 2; mi++) {
#pragma unroll
        for (int ni = 0; ni < 8; ni++) {
            int n = ni * 16 + row16;
#pragma unroll
            for (int r = 0; r < 4; r++)
                np_[(size_t)(mi * 16 + kgrp * 4 + r) * OUT_F + n] = (unsigned short)f2bf(acc[mi][ni][r]);
        }
    }
}

// ---------------------------------------------------------------- finalize: reduce bf16 splits, /l, +rnd, elu
__global__ __launch_bounds__(256) void finalize(const unsigned short* __restrict__ num,
                                                const float* __restrict__ lpart,
                                                const float* __restrict__ rnd,
                                                float* __restrict__ out) {
    int idx = blockIdx.x * 256 + threadIdx.x;   // one thread = 8 outputs
    int m = idx >> 4;
    int c = (idx & 15) * 8;
    size_t g = (size_t)m * OUT_F + c;

    float nm[8] = {};
#pragma unroll
    for (int bk = 0; bk < SPLITK; bk++) {
        u16x8 v = *(const u16x8*)(num + (size_t)bk * N * OUT_F + g);
#pragma unroll
        for (int e = 0; e < 8; e++) nm[e] += __uint_as_float((unsigned)v[e] << 16);
    }
    float l = 0.f;
#pragma unroll
    for (int bk = 0; bk < SPLITK; bk++) l += lpart[(size_t)bk * N + m];
    float inv = 1.f / fmaxf(l, 1e-30f);

    float4 r0 = *(const float4*)(rnd + g);
    float4 r1 = *(const float4*)(rnd + g + 4);
    float rv[8] = { r0.x, r0.y, r0.z, r0.w, r1.x, r1.y, r1.z, r1.w };
    float ov[8];
#pragma unroll
    for (int e = 0; e < 8; e++) {
        float x = (nm[e] * inv + rv[e]) * 1e-5f;
        ov[e] = x > 0.f ? x : __expf(x) - 1.f;
    }
    *(float4*)(out + g)     = make_float4(ov[0], ov[1], ov[2], ov[3]);
    *(float4*)(out + g + 4) = make_float4(ov[4], ov[5], ov[6], ov[7]);
}

extern "C" void kernel_launch(void* const* d_in, const int* in_sizes, int n_in,
                              void* d_out, int out_size, void* d_ws, size_t ws_size,
                              hipStream_t stream) {
    const float* h   = (const float*)d_in[0];
    const int*   adj = (const int*)d_in[1];
    const float* W   = (const float*)d_in[2];
    const float* a   = (const float*)d_in[3];
    const float* rnd = (const float*)d_in[4];
    float* out = (float*)d_out;

    char* w = (char*)d_ws;
    short* WT    = (short*)(w);                            // 131072
    short* WhT   = (short*)(w + 131072);                   // 2097152 -> 2228224
    float* sv    = (float*)(w + 2228224);                  // 32768   -> 2260992
    float* tv    = (float*)(w + 2260992);                  // 32768   -> 2293760
    float* lpart = (float*)(w + 2293760);                  // 262144  -> 2555904
    unsigned char* maskR = (unsigned char*)(w + 2555904);  // 8388608 -> 10944512
    unsigned short* num  = (unsigned short*)(w + 10944512);// 16777216 -> 27721728 (~27 MB)

    conv_W  <<<256, 256, 0, stream>>>(W, WT);
    mkmask  <<<2048, 256, 0, stream>>>(adj, maskR);
    gemm_hW <<<512, 256, 0, stream>>>(h, WT, a, WhT, sv, tv);
    attn    <<<dim3(64, SPLITK), 256, 0, stream>>>(maskR, WhT, sv, tv, num, lpart);
    finalize<<<(N * OUT_F / 8) / 256, 256, 0, stream>>>(num, lpart, rnd, out);
}

// Round 10
// 408.626 us; speedup vs baseline: 1.2476x; 1.2476x over previous
//
#include <hip/hip_runtime.h>

#define N 8192
#define IN_F 512
#define OUT_F 128
#define NW (N / 8)
#define SPLITK 8
#define KC 1024
#define LOG2E 1.4426950408889634f
#define LN2 0.6931471805599453f

typedef __attribute__((ext_vector_type(4))) float f32x4;
typedef __attribute__((ext_vector_type(8))) short bf16x8;
typedef __attribute__((ext_vector_type(8))) unsigned short u16x8;
typedef __attribute__((ext_vector_type(4))) int i32x4;

__device__ __forceinline__ short f2bf(float f) {
    union { float f; unsigned u; } c; c.f = f;
    unsigned r = c.u + 0x7FFFu + ((c.u >> 16) & 1u);
    return (short)(r >> 16);
}

__device__ __forceinline__ float exp2fast(float x) {
#if __has_builtin(__builtin_amdgcn_exp2f)
    return __builtin_amdgcn_exp2f(x);
#else
    return __expf(x * LN2);
#endif
}

__device__ __forceinline__ void load_lds16(const void* g, void* l) {
    __builtin_amdgcn_global_load_lds((const __attribute__((address_space(1))) unsigned*)g,
                                     (__attribute__((address_space(3))) unsigned*)l,
                                     16, 0, 0);
}

// ---------------------------------------------------------------- prep: blocks [0,2048) mkmask, [2048,2304) conv_W
// mkmask: adj int32 -> row-major bitmask (pure stream, NT loads: zero reuse)
__global__ __launch_bounds__(256) void prep(const int* __restrict__ adj,
                                            unsigned char* __restrict__ maskR,
                                            const float* __restrict__ W,
                                            short* __restrict__ WT) {
    if (blockIdx.x >= 2048) {
        int idx = (blockIdx.x - 2048) * 256 + threadIdx.x;   // 65536 total
        int n = idx & (OUT_F - 1);
        int k = idx >> 7;
        WT[(size_t)n * IN_F + k] = f2bf(W[idx]);
        return;
    }
    const int wave = threadIdx.x >> 6, lane = threadIdx.x & 63;
    const size_t m = (size_t)blockIdx.x * 4 + wave;
    const i32x4* ap = (const i32x4*)(adj + m * N);
    unsigned char* mp = maskR + m * NW;
#pragma unroll 4
    for (int it = 0; it < 16; it++) {
        int b4 = it * 128 + lane * 2;
        i32x4 a0 = __builtin_nontemporal_load(ap + b4);
        i32x4 a1 = __builtin_nontemporal_load(ap + b4 + 1);
        unsigned b = (unsigned)(a0.x > 0) | ((unsigned)(a0.y > 0) << 1) |
                     ((unsigned)(a0.z > 0) << 2) | ((unsigned)(a0.w > 0) << 3) |
                     ((unsigned)(a1.x > 0) << 4) | ((unsigned)(a1.y > 0) << 5) |
                     ((unsigned)(a1.z > 0) << 6) | ((unsigned)(a1.w > 0) << 7);
        mp[it * 64 + lane] = (unsigned char)b;
    }
}

// ---------------------------------------------------------------- gemm_hW: Wh=h@W -> WhT bf16 [OUT_F][N]; fused s,t (x LOG2E)
__global__ __launch_bounds__(256) void gemm_hW(const float* __restrict__ h,
                                               const short* __restrict__ WT,
                                               const float* __restrict__ a,
                                               short* __restrict__ WhT,
                                               float* __restrict__ sOut,
                                               float* __restrict__ tOut) {
    const int tid = threadIdx.x;
    const int wave = tid >> 6, lane = tid & 63;
    const int row16 = lane & 15, kgrp = lane >> 4;
    const int m0 = blockIdx.x * 16;
    const int kbase = wave * 128;

    f32x4 acc[8] = {};
    const float4* hp = (const float4*)(h + (size_t)(m0 + row16) * IN_F + kbase);

#pragma unroll
    for (int kk = 0; kk < 128; kk += 32) {
        float4 u0 = hp[kk / 4 + kgrp * 2];
        float4 u1 = hp[kk / 4 + kgrp * 2 + 1];
        bf16x8 af;
        af[0] = f2bf(u0.x); af[1] = f2bf(u0.y); af[2] = f2bf(u0.z); af[3] = f2bf(u0.w);
        af[4] = f2bf(u1.x); af[5] = f2bf(u1.y); af[6] = f2bf(u1.z); af[7] = f2bf(u1.w);
#pragma unroll
        for (int nt = 0; nt < 8; nt++) {
            bf16x8 bf_ = *(const bf16x8*)(WT + (size_t)(nt * 16 + row16) * IN_F + kbase + kk + kgrp * 8);
            acc[nt] = __builtin_amdgcn_mfma_f32_16x16x32_bf16(af, bf_, acc[nt], 0, 0, 0);
        }
    }

    __shared__ float red[4][16][132];
#pragma unroll
    for (int nt = 0; nt < 8; nt++)
#pragma unroll
        for (int r = 0; r < 4; r++)
            red[wave][kgrp * 4 + r][nt * 16 + row16] = acc[nt][r];
    __syncthreads();

    const int row = tid >> 4, seg = tid & 15;
    float v[8];
#pragma unroll
    for (int e = 0; e < 8; e++) {
        int c = seg * 8 + e;
        v[e] = red[0][row][c] + red[1][row][c] + red[2][row][c] + red[3][row][c];
    }
    float sp = 0.f, tp = 0.f;
#pragma unroll
    for (int e = 0; e < 8; e++) {
        sp += v[e] * a[seg * 8 + e];
        tp += v[e] * a[OUT_F + seg * 8 + e];
    }
    sp += __shfl_xor(sp, 1); tp += __shfl_xor(tp, 1);
    sp += __shfl_xor(sp, 2); tp += __shfl_xor(tp, 2);
    sp += __shfl_xor(sp, 4); tp += __shfl_xor(tp, 4);
    sp += __shfl_xor(sp, 8); tp += __shfl_xor(tp, 8);
    if (seg == 0) {
        sOut[m0 + row] = sp * LOG2E;
        tOut[m0 + row] = tp * LOG2E;
    }
#pragma unroll
    for (int e = 0; e < 8; e++)
        WhT[(size_t)(seg * 8 + e) * N + m0 + row] = f2bf(v[e]);
}

// ---------------------------------------------------------------- attn: mask-driven, B via async-LDS pipeline
// 1-D grid 1024; kb = blockIdx.x & 7 -> XCD-pinned K-slice (round-robin dispatch);
// 256 thr = 4 waves; wave = 16M x 128N x 1024K
__global__ __launch_bounds__(256, 4) void attn(const unsigned char* __restrict__ maskR,
                                               const short* __restrict__ WhT,
                                               const float* __restrict__ s,
                                               const float* __restrict__ t,
                                               unsigned short* __restrict__ num,
                                               float* __restrict__ lpart) {
    const int tid = threadIdx.x;
    const int wave = tid >> 6, lane = tid & 63;
    const int row16 = lane & 15, kgrp = lane >> 4;
    const int kb = blockIdx.x & 7;          // XCD-pin: all blocks on an XCD share this K-slice
    const int mb = blockIdx.x >> 3;
    const int m0 = mb * 64 + wave * 16;
    const int m  = m0 + row16;
    const int ks = kb * KC;

    __shared__ short Bs[2][2][128 * 32];   // 32 KB: [parity][slice][n*32+k]
    __shared__ float tl[KC];               // 4 KB

    for (int i = tid; i < KC; i += 256) tl[i] = t[ks + i];

    const float s_m = s[m];
    const int4* mp = (const int4*)(maskR + (size_t)m * NW + (ks >> 3));  // 8 int4 = 128 B
    int4 mcur = mp[0], mnxt = mp[1];

    auto stageB = [&](int sup, int par) {
        const int k0 = ks + sup * 64;
#pragma unroll
        for (int d = 0; d < 2; d++)
#pragma unroll
            for (int q = 0; q < 2; q++) {
                int nrow = wave * 32 + q * 16 + (lane >> 2);
                const short* g = WhT + (size_t)nrow * N + k0 + d * 32 + (lane & 3) * 8;
                load_lds16(g, &Bs[par][d][(wave * 32 + q * 16) * 32]);
            }
    };

    f32x4 acc[8] = {};
    float lsum = 0.f;

    stageB(0, 0);
    __syncthreads();   // tl + B super 0 ready

    for (int sp2 = 0; sp2 < 8; sp2++) {          // mcur = mask int4 #sp2 (slices sp2*4..+3)
#pragma unroll
        for (int ss = 0; ss < 2; ss++) {
            const int sp = sp2 * 2 + ss;         // super 0..15
            const int par = sp & 1;
            if (sp + 1 < 16) stageB(sp + 1, par ^ 1);   // async into other parity
#pragma unroll
            for (int d = 0; d < 2; d++) {
                const int g = sp * 2 + d;        // slice 0..31 (g>>2 == sp2, g&3 == ss*2+d)
                const unsigned dw = (unsigned)((const int*)&mcur)[ss * 2 + d];
                const unsigned mbyte = (dw >> (kgrp * 8)) & 0xFFu;

                const float* tp = tl + g * 32 + kgrp * 8;
                float4 tA = *(const float4*)tp;
                float4 tB = *(const float4*)(tp + 4);
                float tv[8] = { tA.x, tA.y, tA.z, tA.w, tB.x, tB.y, tB.z, tB.w };

                bf16x8 bfr[8];
                const short* base = &Bs[par][d][0];
#pragma unroll
                for (int ni = 0; ni < 8; ni++)
                    bfr[ni] = *(const bf16x8*)(base + (ni * 16 + row16) * 32 + kgrp * 8);

                unsigned pu[8];
#pragma unroll
                for (int e = 0; e < 8; e++) {
                    float x = s_m + tv[e];
                    x = fmaxf(x, 0.2f * x);                    // leaky relu
                    float p = exp2fast(x);                     // s,t pre-scaled by log2e
                    unsigned u = __float_as_uint(p) & 0xFFFF0000u;
                    u = ((mbyte >> e) & 1u) ? u : 0u;
                    lsum += __uint_as_float(u);                // consistent with numerator
                    pu[e] = u;
                }
                bf16x8 af;
                unsigned* au = (unsigned*)&af;
#pragma unroll
                for (int q = 0; q < 4; q++) au[q] = (pu[2 * q] >> 16) | pu[2 * q + 1];
#pragma unroll
                for (int ni = 0; ni < 8; ni++)
                    acc[ni] = __builtin_amdgcn_mfma_f32_16x16x32_bf16(af, bfr[ni], acc[ni], 0, 0, 0);
            }
            __syncthreads();   // drains stage of sp+1; guards parity reuse
        }
        mcur = mnxt;
        if (sp2 + 2 < 8) mnxt = mp[sp2 + 2];
    }

    // row sum across kgrp lanes
    {
        float v = lsum;
        v += __shfl_xor(v, 16);
        v += __shfl_xor(v, 32);
        if (kgrp == 0) lpart[(size_t)kb * N + m] = v;
    }

    // partial numerator, bf16: C layout row = kgrp*4+r (m within 16), col = ni*16+row16
    unsigned short* np_ = num + ((size_t)kb * N + m0) * OUT_F;
#pragma unroll
    for (int ni = 0; ni < 8; ni++) {
        int n = ni * 16 + row16;
#pragma unroll
        for (int r = 0; r < 4; r++)
            np_[(size_t)(kgrp * 4 + r) * OUT_F + n] = (unsigned short)f2bf(acc[ni][r]);
    }
}

// ---------------------------------------------------------------- finalize: reduce bf16 splits, /l, +rnd, elu
__global__ __launch_bounds__(256) void finalize(const unsigned short* __restrict__ num,
                                                const float* __restrict__ lpart,
                                                const float* __restrict__ rnd,
                                                float* __restrict__ out) {
    int idx = blockIdx.x * 256 + threadIdx.x;   // one thread = 8 outputs
    int m = idx >> 4;
    int c = (idx & 15) * 8;
    size_t g = (size_t)m * OUT_F + c;

    float nm[8] = {};
#pragma unroll
    for (int bk = 0; bk < SPLITK; bk++) {
        u16x8 v = *(const u16x8*)(num + (size_t)bk * N * OUT_F + g);
#pragma unroll
        for (int e = 0; e < 8; e++) nm[e] += __uint_as_float((unsigned)v[e] << 16);
    }
    float l = 0.f;
#pragma unroll
    for (int bk = 0; bk < SPLITK; bk++) l += lpart[(size_t)bk * N + m];
    float inv = 1.f / fmaxf(l, 1e-30f);

    float4 r0 = *(const float4*)(rnd + g);
    float4 r1 = *(const float4*)(rnd + g + 4);
    float rv[8] = { r0.x, r0.y, r0.z, r0.w, r1.x, r1.y, r1.z, r1.w };
    float ov[8];
#pragma unroll
    for (int e = 0; e < 8; e++) {
        float x = (nm[e] * inv + rv[e]) * 1e-5f;
        ov[e] = x > 0.f ? x : __expf(x) - 1.f;
    }
    *(float4*)(out + g)     = make_float4(ov[0], ov[1], ov[2], ov[3]);
    *(float4*)(out + g + 4) = make_float4(ov[4], ov[5], ov[6], ov[7]);
}

extern "C" void kernel_launch(void* const* d_in, const int* in_sizes, int n_in,
                              void* d_out, int out_size, void* d_ws, size_t ws_size,
                              hipStream_t stream) {
    const float* h   = (const float*)d_in[0];
    const int*   adj = (const int*)d_in[1];
    const float* W   = (const float*)d_in[2];
    const float* a   = (const float*)d_in[3];
    const float* rnd = (const float*)d_in[4];
    float* out = (float*)d_out;

    char* w = (char*)d_ws;
    short* WT    = (short*)(w);                            // 131072
    short* WhT   = (short*)(w + 131072);                   // 2097152 -> 2228224
    float* sv    = (float*)(w + 2228224);                  // 32768   -> 2260992
    float* tv    = (float*)(w + 2260992);                  // 32768   -> 2293760
    float* lpart = (float*)(w + 2293760);                  // 262144  -> 2555904
    unsigned char* maskR = (unsigned char*)(w + 2555904);  // 8388608 -> 10944512
    unsigned short* num  = (unsigned short*)(w + 10944512);// 16777216 -> 27721728 (~27 MB)

    prep    <<<2304, 256, 0, stream>>>(adj, maskR, W, WT);
    gemm_hW <<<512, 256, 0, stream>>>(h, WT, a, WhT, sv, tv);
    attn    <<<1024, 256, 0, stream>>>(maskR, WhT, sv, tv, num, lpart);
    finalize<<<(N * OUT_F / 8) / 256, 256, 0, stream>>>(num, lpart, rnd, out);
}